// Round 6
// baseline (133.784 us; speedup 1.0000x reference)
//
#include <hip/hip_runtime.h>
#include <hip/hip_bf16.h>
#include <hip/hip_fp16.h>

#define Bn 2048
#define Tn 128
#define Vn 256
#define Cn 32
#define Hn 128
#define En 256
#define On 256
#define Gn 384
#define BNn 32

typedef _Float16 f16;
typedef __attribute__((ext_vector_type(8))) _Float16 h8;
typedef __attribute__((ext_vector_type(4))) float f4;

#define LOG2E 1.4426950408889634f

__device__ __forceinline__ float fexp2(float x) { return __builtin_amdgcn_exp2f(x); }
__device__ __forceinline__ float frcp(float x) { return __builtin_amdgcn_rcpf(x); }

// ---------------- Kernel 1: packed scaled xp table (f32) ----------------
// xt[dir][v][j][4] = { -log2e*(xr+bir+bhhr), -log2e*(xz+biz+bhhz), 2log2e*(xn+bin), 0 }
// b_hh folded for r/z (additive in reference); n-gate b_hh stays in MFMA C-init.
__global__ void build_table_k(const float* __restrict__ emb,
                              const float* __restrict__ wf,
                              const float* __restrict__ bif,
                              const float* __restrict__ bhf,
                              const float* __restrict__ wb,
                              const float* __restrict__ bib,
                              const float* __restrict__ bhb,
                              float* __restrict__ xt) {
  const int dir = blockIdx.x >> 8;
  const int v = blockIdx.x & 255;
  const int j = threadIdx.x;  // 128 threads
  const float* w = dir ? wb : wf;
  const float* bi = dir ? bib : bif;
  const float* bh = dir ? bhb : bhf;
  const float sc[3] = {-LOG2E, -LOG2E, 2.0f * LOG2E};
  f4 o;
  o[3] = 0.f;
#pragma unroll
  for (int ga = 0; ga < 3; ++ga) {
    const int g = ga * Hn + j;
    float acc = bi[g] + (ga < 2 ? bh[g] : 0.f);
    const f4* wr = (const f4*)(w + g * Cn);
    const f4* er = (const f4*)(emb + v * Cn);
#pragma unroll
    for (int q = 0; q < 8; ++q) {
      f4 wv = wr[q], ev = er[q];
      acc = fmaf(ev.x, wv.x, acc);
      acc = fmaf(ev.y, wv.y, acc);
      acc = fmaf(ev.z, wv.z, acc);
      acc = fmaf(ev.w, wv.w, acc);
    }
    o[ga] = acc * sc[ga];
  }
  *(f4*)&xt[((dir * Vn + v) * Hn + j) * 4] = o;
}

// ---------------- Kernel 2: bidirectional GRU ----------------
// 256 blocks: dir = bi&1, 16 samples, 8 waves x 16 j. h fragment-major
// (byte(k,m) = (k>>3)*256 + m*16 + (k&7)*2) XOR-32 swizzled, double-buffered.
// xp + tokens prefetched one step ahead; barrier drains lgkmcnt only.
__launch_bounds__(512, 2)
__global__ void gru_k(const int* __restrict__ tokens,
                      const float* __restrict__ whhf,
                      const float* __restrict__ bhhf,
                      const float* __restrict__ whhb,
                      const float* __restrict__ bhhb,
                      const float* __restrict__ xt,
                      float* __restrict__ feat) {
  const int dir = blockIdx.x & 1;
  const int b0 = (blockIdx.x >> 1) * 16;
  const int tid = threadIdx.x;
  const int wv = tid >> 6;
  const int ln = tid & 63;
  const int lr = ln & 15;
  const int lg = ln >> 4;
  const int j = wv * 16 + lr;

  __shared__ f16 hfrag[2 * 2048];  // 2 x 4KB, XOR-32 swizzled
  __shared__ int tokT[Tn * 16];    // [t][s], direction-adjusted

  for (int i = tid; i < Tn * 16; i += 512) {
    const int t = i >> 4, s = i & 15;
    tokT[i] = tokens[(b0 + s) * Tn + (dir ? (Tn - 1 - t) : t)];
  }
  for (int i = tid; i < 2 * 2048; i += 512) hfrag[i] = (f16)0.f;

  const float* whh = dir ? whhb : whhf;
  const float* bhh = dir ? bhhb : bhhf;
  const char* tab = (const char*)(xt + dir * (Vn * Hn * 4));

  // register-resident gate-scaled B frags
  const float gsc[3] = {-LOG2E, -LOG2E, 2.0f * LOG2E};
  h8 Bf[3][4];
#pragma unroll
  for (int ga = 0; ga < 3; ++ga) {
    const float* wr = whh + (ga * Hn + j) * Hn + lg * 8;
#pragma unroll
    for (int kk = 0; kk < 4; ++kk) {
      h8 b;
#pragma unroll
      for (int i = 0; i < 8; ++i) b[i] = (f16)(wr[kk * 32 + i] * gsc[ga]);
      Bf[ga][kk] = b;
    }
  }
  const float b2 = bhh[2 * Hn + j] * (2.0f * LOG2E);
  const f4 BH2 = {b2, b2, b2, b2};
  const f4 Z4 = {0.f, 0.f, 0.f, 0.f};

  __syncthreads();  // tokT + hfrag zeros visible

  // precomputed LDS byte addresses (loop-invariant; buffer/kk via offset imm)
  const int aadr = (lg * 256 + lr * 16) ^ ((lg & 1) << 5);
  int wadr[4];
  {
    const int wmask = ((j >> 3) & 1) << 5;
    const int wbase = (j >> 3) * 256 + (j & 7) * 2 + lg * 64;
#pragma unroll
    for (int r = 0; r < 4; ++r) wadr[r] = (wbase + r * 16) ^ wmask;
  }
  const int tadr = lg * 16;  // + t*64
  const int jb = j * 16;     // byte offset in table row (f32 x4)

  // prologue: tokens(0) -> xc loads; tokens(1) -> tkB
  int4 tkA = *(const int4*)((const char*)tokT + tadr);
  f4 xc0, xc1, xc2, xc3, xn0, xn1, xn2, xn3;
  xc0 = *(const f4*)(tab + ((long)tkA.x << 11) + jb);
  xc1 = *(const f4*)(tab + ((long)tkA.y << 11) + jb);
  xc2 = *(const f4*)(tab + ((long)tkA.z << 11) + jb);
  xc3 = *(const f4*)(tab + ((long)tkA.w << 11) + jb);
  int4 tkB = *(const int4*)((const char*)tokT + 64 + tadr);

  float h0 = 0.f, h1 = 0.f, h2 = 0.f, h3 = 0.f;

#define GRU_BODY(T, P, C0, C1, C2, C3, N0, N1, N2, N3, TKc, TKn)               \
  {                                                                            \
    N0 = *(const f4*)(tab + ((long)TKc.x << 11) + jb);                         \
    N1 = *(const f4*)(tab + ((long)TKc.y << 11) + jb);                         \
    N2 = *(const f4*)(tab + ((long)TKc.z << 11) + jb);                         \
    N3 = *(const f4*)(tab + ((long)TKc.w << 11) + jb);                         \
    {                                                                          \
      const int tt = ((T) + 2 < Tn) ? ((T) + 2) : (Tn - 1);                    \
      TKn = *(const int4*)((const char*)tokT + tt * 64 + tadr);                \
    }                                                                          \
    const char* hb = (const char*)hfrag + (P) * 4096;                          \
    h8 A0 = *(const h8*)(hb + aadr + 0 * 1024);                                \
    h8 A1 = *(const h8*)(hb + aadr + 1 * 1024);                                \
    h8 A2 = *(const h8*)(hb + aadr + 2 * 1024);                                \
    h8 A3 = *(const h8*)(hb + aadr + 3 * 1024);                                \
    f4 aR = __builtin_amdgcn_mfma_f32_16x16x32_f16(A0, Bf[0][0], Z4, 0, 0, 0); \
    f4 aZ = __builtin_amdgcn_mfma_f32_16x16x32_f16(A0, Bf[1][0], Z4, 0, 0, 0); \
    f4 aN = __builtin_amdgcn_mfma_f32_16x16x32_f16(A0, Bf[2][0], BH2, 0, 0, 0);\
    aR = __builtin_amdgcn_mfma_f32_16x16x32_f16(A1, Bf[0][1], aR, 0, 0, 0);    \
    aZ = __builtin_amdgcn_mfma_f32_16x16x32_f16(A1, Bf[1][1], aZ, 0, 0, 0);    \
    aN = __builtin_amdgcn_mfma_f32_16x16x32_f16(A1, Bf[2][1], aN, 0, 0, 0);    \
    aR = __builtin_amdgcn_mfma_f32_16x16x32_f16(A2, Bf[0][2], aR, 0, 0, 0);    \
    aZ = __builtin_amdgcn_mfma_f32_16x16x32_f16(A2, Bf[1][2], aZ, 0, 0, 0);    \
    aN = __builtin_amdgcn_mfma_f32_16x16x32_f16(A2, Bf[2][2], aN, 0, 0, 0);    \
    aR = __builtin_amdgcn_mfma_f32_16x16x32_f16(A3, Bf[0][3], aR, 0, 0, 0);    \
    aZ = __builtin_amdgcn_mfma_f32_16x16x32_f16(A3, Bf[1][3], aZ, 0, 0, 0);    \
    aN = __builtin_amdgcn_mfma_f32_16x16x32_f16(A3, Bf[2][3], aN, 0, 0, 0);    \
    char* hw = (char*)hfrag + ((P) ^ 1) * 4096;                                \
    {                                                                          \
      const float rg = frcp(1.f + fexp2(C0.x + aR[0]));                        \
      const float zg = frcp(1.f + fexp2(C0.y + aZ[0]));                        \
      const float ng = fmaf(-2.f, frcp(1.f + fexp2(fmaf(rg, aN[0], C0.z))), 1.f); \
      h0 = fmaf(zg, h0 - ng, ng);                                              \
      *(f16*)(hw + wadr[0]) = (f16)h0;                                         \
    }                                                                          \
    {                                                                          \
      const float rg = frcp(1.f + fexp2(C1.x + aR[1]));                        \
      const float zg = frcp(1.f + fexp2(C1.y + aZ[1]));                        \
      const float ng = fmaf(-2.f, frcp(1.f + fexp2(fmaf(rg, aN[1], C1.z))), 1.f); \
      h1 = fmaf(zg, h1 - ng, ng);                                              \
      *(f16*)(hw + wadr[1]) = (f16)h1;                                         \
    }                                                                          \
    {                                                                          \
      const float rg = frcp(1.f + fexp2(C2.x + aR[2]));                        \
      const float zg = frcp(1.f + fexp2(C2.y + aZ[2]));                        \
      const float ng = fmaf(-2.f, frcp(1.f + fexp2(fmaf(rg, aN[2], C2.z))), 1.f); \
      h2 = fmaf(zg, h2 - ng, ng);                                              \
      *(f16*)(hw + wadr[2]) = (f16)h2;                                         \
    }                                                                          \
    {                                                                          \
      const float rg = frcp(1.f + fexp2(C3.x + aR[3]));                        \
      const float zg = frcp(1.f + fexp2(C3.y + aZ[3]));                        \
      const float ng = fmaf(-2.f, frcp(1.f + fexp2(fmaf(rg, aN[3], C3.z))), 1.f); \
      h3 = fmaf(zg, h3 - ng, ng);                                              \
      *(f16*)(hw + wadr[3]) = (f16)h3;                                         \
    }                                                                          \
    asm volatile("s_waitcnt lgkmcnt(0)\n\ts_barrier" ::: "memory");            \
  }

#pragma unroll 1
  for (int t = 0; t < Tn; t += 2) {
    GRU_BODY(t, 0, xc0, xc1, xc2, xc3, xn0, xn1, xn2, xn3, tkB, tkA)
    GRU_BODY(t + 1, 1, xn0, xn1, xn2, xn3, xc0, xc1, xc2, xc3, tkA, tkB)
  }
#undef GRU_BODY

  feat[(b0 + lg * 4 + 0) * En + dir * Hn + j] = h0;
  feat[(b0 + lg * 4 + 1) * En + dir * Hn + j] = h1;
  feat[(b0 + lg * 4 + 2) * En + dir * Hn + j] = h2;
  feat[(b0 + lg * 4 + 3) * En + dir * Hn + j] = h3;
}

// ---------------- Kernel 3: adapter + LN + proj ----------------
__launch_bounds__(256, 2)
__global__ void epi_k(const float* __restrict__ feat,
                      const int* __restrict__ lang_ids,
                      const float* __restrict__ down_w,
                      const float* __restrict__ down_b,
                      const float* __restrict__ up_w,
                      const float* __restrict__ up_b,
                      const float* __restrict__ ln_g,
                      const float* __restrict__ ln_b,
                      const float* __restrict__ proj_w,
                      const float* __restrict__ proj_b,
                      float* __restrict__ out) {
  const int tid = threadIdx.x;
  const int wv = tid >> 6, ln = tid & 63;
  const int b0 = blockIdx.x * 8;

  __shared__ float fl[8][En];
  __shared__ f16 yA[16][En + 8];

#pragma unroll
  for (int s = 0; s < 8; ++s) fl[s][tid] = feat[(b0 + s) * En + tid];
  {
    f16* z = &yA[0][0];
    for (int i = tid; i < 16 * (En + 8); i += 256) z[i] = (f16)0.f;
  }
  __syncthreads();

#pragma unroll 1
  for (int si = 0; si < 2; ++si) {
    const int s = wv * 2 + si;
    const int lang = lang_ids[b0 + s];

    const int d = ln & 31, hf = ln >> 5;
    const f4* dwv = (const f4*)(down_w + (lang * BNn + d) * En + hf * 128);
    const f4* fsv = (const f4*)&fl[s][hf * 128];
    float pacc = 0.f;
#pragma unroll
    for (int q = 0; q < 32; ++q) {
      f4 a = fsv[q], w = dwv[q];
      pacc = fmaf(a.x, w.x, pacc);
      pacc = fmaf(a.y, w.y, pacc);
      pacc = fmaf(a.z, w.z, pacc);
      pacc = fmaf(a.w, w.w, pacc);
    }
    pacc += __shfl_xor(pacc, 32);
    const float hv = pacc + down_b[lang * BNn + d];
    const float hid = 0.5f * hv * (1.0f + erff(hv * 0.70710678118f));

    float hh[32];
#pragma unroll
    for (int dd = 0; dd < 32; ++dd) hh[dd] = __shfl(hid, dd);

    const int e0 = ln * 4;
    float x[4];
    float s1 = 0.f, s2 = 0.f;
#pragma unroll
    for (int i = 0; i < 4; ++i) {
      const f4* ur = (const f4*)(up_w + (lang * En + e0 + i) * BNn);
      float a = 0.f;
#pragma unroll
      for (int q = 0; q < 8; ++q) {
        f4 u = ur[q];
        a = fmaf(hh[q * 4 + 0], u.x, a);
        a = fmaf(hh[q * 4 + 1], u.y, a);
        a = fmaf(hh[q * 4 + 2], u.z, a);
        a = fmaf(hh[q * 4 + 3], u.w, a);
      }
      x[i] = a + fl[s][e0 + i] + up_b[lang * En + e0 + i];
      s1 += x[i];
      s2 = fmaf(x[i], x[i], s2);
    }
#pragma unroll
    for (int off = 32; off >= 1; off >>= 1) {
      s1 += __shfl_xor(s1, off);
      s2 += __shfl_xor(s2, off);
    }
    const float mu = s1 * (1.0f / En);
    const float var = s2 * (1.0f / En) - mu * mu;
    const float rs = rsqrtf(var + 1e-5f);
#pragma unroll
    for (int i = 0; i < 4; ++i) {
      const float yv = (x[i] - mu) * rs * ln_g[lang * En + e0 + i] + ln_b[lang * En + e0 + i];
      yA[s][e0 + i] = (f16)yv;
    }
  }
  __syncthreads();

  const int lr = ln & 15, lg = ln >> 4;
  f4 acc[4];
#pragma unroll
  for (int tt = 0; tt < 4; ++tt) {
    const float pb = proj_b[wv * 64 + tt * 16 + lr];
    acc[tt] = (f4){pb, pb, pb, pb};
  }
#pragma unroll
  for (int kk = 0; kk < 8; ++kk) {
    h8 aF = *(const h8*)(&yA[lr][kk * 32 + lg * 8]);
#pragma unroll
    for (int tt = 0; tt < 4; ++tt) {
      const int o0 = wv * 64 + tt * 16;
      const float* pw = proj_w + (o0 + lr) * En + kk * 32 + lg * 8;
      h8 bF;
#pragma unroll
      for (int i = 0; i < 8; ++i) bF[i] = (f16)pw[i];
      acc[tt] = __builtin_amdgcn_mfma_f32_16x16x32_f16(aF, bF, acc[tt], 0, 0, 0);
    }
  }
  if (lg < 2) {
#pragma unroll
    for (int tt = 0; tt < 4; ++tt) {
      const int o0 = wv * 64 + tt * 16;
#pragma unroll
      for (int r = 0; r < 4; ++r)
        out[(b0 + lg * 4 + r) * On + o0 + lr] = acc[tt][r];
    }
  }
}

extern "C" void kernel_launch(void* const* d_in, const int* in_sizes, int n_in,
                              void* d_out, int out_size, void* d_ws, size_t ws_size,
                              hipStream_t stream) {
  const int* tokens = (const int*)d_in[0];
  const int* lang_ids = (const int*)d_in[1];
  const float* emb = (const float*)d_in[2];
  const float* w_ih_f = (const float*)d_in[3];
  const float* w_hh_f = (const float*)d_in[4];
  const float* b_ih_f = (const float*)d_in[5];
  const float* b_hh_f = (const float*)d_in[6];
  const float* w_ih_b = (const float*)d_in[7];
  const float* w_hh_b = (const float*)d_in[8];
  const float* b_ih_b = (const float*)d_in[9];
  const float* b_hh_b = (const float*)d_in[10];
  const float* down_w = (const float*)d_in[11];
  const float* down_b = (const float*)d_in[12];
  const float* up_w = (const float*)d_in[13];
  const float* up_b = (const float*)d_in[14];
  const float* ln_g = (const float*)d_in[15];
  const float* ln_b = (const float*)d_in[16];
  const float* proj_w = (const float*)d_in[17];
  const float* proj_b = (const float*)d_in[18];

  float* xt = (float*)d_ws;                                    // [2][256][128][4] f32 = 2MB
  float* feat = (float*)((char*)d_ws + 2 * Vn * Hn * 4 * 4);   // [2048][256] f32

  build_table_k<<<dim3(512), dim3(128), 0, stream>>>(emb, w_ih_f, b_ih_f, b_hh_f,
                                                     w_ih_b, b_ih_b, b_hh_b, xt);
  gru_k<<<dim3(256), dim3(512), 0, stream>>>(tokens, w_hh_f, b_hh_f, w_hh_b, b_hh_b, xt, feat);
  epi_k<<<dim3(256), dim3(256), 0, stream>>>(feat, lang_ids, down_w, down_b, up_w, up_b,
                                             ln_g, ln_b, proj_w, proj_b, (float*)d_out);
}

// Round 7
// 124.765 us; speedup vs baseline: 1.0723x; 1.0723x over previous
//
#include <hip/hip_runtime.h>
#include <hip/hip_bf16.h>
#include <hip/hip_fp16.h>

#define Bn 2048
#define Tn 128
#define Vn 256
#define Cn 32
#define Hn 128
#define En 256
#define On 256
#define Gn 384
#define BNn 32

typedef _Float16 f16;
typedef __attribute__((ext_vector_type(8))) _Float16 h8;
typedef __attribute__((ext_vector_type(4))) _Float16 h4;
typedef __attribute__((ext_vector_type(4))) float f4;

#define LOG2E 1.4426950408889634f

__device__ __forceinline__ f16 hexp2(f16 x) {
  f16 r;
  asm("v_exp_f16 %0, %1" : "=v"(r) : "v"(x));
  return r;
}
__device__ __forceinline__ f16 hrcp(f16 x) {
  f16 r;
  asm("v_rcp_f16 %0, %1" : "=v"(r) : "v"(x));
  return r;
}

// ---------------- Kernel 1: packed scaled xp table (f16) ----------------
// xt[dir][v][j][4] = { -log2e*(xr+bir+bhhr), -log2e*(xz+biz+bhhz), 2log2e*(xn+bin), 0 }
__global__ void build_table_k(const float* __restrict__ emb,
                              const float* __restrict__ wf,
                              const float* __restrict__ bif,
                              const float* __restrict__ bhf,
                              const float* __restrict__ wb,
                              const float* __restrict__ bib,
                              const float* __restrict__ bhb,
                              f16* __restrict__ xt) {
  const int dir = blockIdx.x >> 8;
  const int v = blockIdx.x & 255;
  const int j = threadIdx.x;  // 128 threads
  const float* w = dir ? wb : wf;
  const float* bi = dir ? bib : bif;
  const float* bh = dir ? bhb : bhf;
  const float sc[3] = {-LOG2E, -LOG2E, 2.0f * LOG2E};
  h4 o;
  o[3] = (f16)0.f;
#pragma unroll
  for (int ga = 0; ga < 3; ++ga) {
    const int g = ga * Hn + j;
    float acc = bi[g] + (ga < 2 ? bh[g] : 0.f);
    const f4* wr = (const f4*)(w + g * Cn);
    const f4* er = (const f4*)(emb + v * Cn);
#pragma unroll
    for (int q = 0; q < 8; ++q) {
      f4 wv = wr[q], ev = er[q];
      acc = fmaf(ev.x, wv.x, acc);
      acc = fmaf(ev.y, wv.y, acc);
      acc = fmaf(ev.z, wv.z, acc);
      acc = fmaf(ev.w, wv.w, acc);
    }
    o[ga] = (f16)(acc * sc[ga]);
  }
  *(h4*)&xt[((dir * Vn + v) * Hn + j) * 4] = o;
}

// ---------------- Kernel 2: bidirectional GRU ----------------
// 256 blocks: dir = bi&1, 16 samples, 8 waves x 16 j. h fragment-major
// (byte(k,m) = (k>>3)*256 + m*16 + (k&7)*2) XOR-32 swizzled, double-buffered.
// A-frag reads issue first-after-barrier; xp (f16x4, 8B) + token (preshifted
// byte offsets) prefetched one step ahead; barrier drains lgkmcnt only.
// Gates entirely in f16 (v_exp_f16 / v_rcp_f16).
__launch_bounds__(512, 2)
__global__ void gru_k(const int* __restrict__ tokens,
                      const float* __restrict__ whhf,
                      const float* __restrict__ bhhf,
                      const float* __restrict__ whhb,
                      const float* __restrict__ bhhb,
                      const f16* __restrict__ xt,
                      float* __restrict__ feat) {
  const int dir = blockIdx.x & 1;
  const int b0 = (blockIdx.x >> 1) * 16;
  const int tid = threadIdx.x;
  const int wv = tid >> 6;
  const int ln = tid & 63;
  const int lr = ln & 15;
  const int lg = ln >> 4;
  const int j = wv * 16 + lr;

  __shared__ f16 hfrag[2 * 2048];  // 2 x 4KB, XOR-32 swizzled
  __shared__ int tokT[Tn * 16];    // [t][s], direction-adjusted, value = tok<<10

  for (int i = tid; i < Tn * 16; i += 512) {
    const int t = i >> 4, s = i & 15;
    tokT[i] = tokens[(b0 + s) * Tn + (dir ? (Tn - 1 - t) : t)] << 10;
  }
  for (int i = tid; i < 2 * 2048; i += 512) hfrag[i] = (f16)0.f;

  const float* whh = dir ? whhb : whhf;
  const float* bhh = dir ? bhhb : bhhf;
  const char* tab = (const char*)(xt + dir * (Vn * Hn * 4));

  // register-resident gate-scaled B frags
  const float gsc[3] = {-LOG2E, -LOG2E, 2.0f * LOG2E};
  h8 Bf[3][4];
#pragma unroll
  for (int ga = 0; ga < 3; ++ga) {
    const float* wr = whh + (ga * Hn + j) * Hn + lg * 8;
#pragma unroll
    for (int kk = 0; kk < 4; ++kk) {
      h8 b;
#pragma unroll
      for (int i = 0; i < 8; ++i) b[i] = (f16)(wr[kk * 32 + i] * gsc[ga]);
      Bf[ga][kk] = b;
    }
  }
  const float b2 = bhh[2 * Hn + j] * (2.0f * LOG2E);
  const f4 BH2 = {b2, b2, b2, b2};
  const f4 Z4 = {0.f, 0.f, 0.f, 0.f};

  __syncthreads();  // tokT + hfrag zeros visible

  // precomputed LDS byte addresses (loop-invariant)
  const int aadr = (lg * 256 + lr * 16) ^ ((lg & 1) << 5);
  int wadr[4];
  {
    const int wmask = ((j >> 3) & 1) << 5;
    const int wbase = (j >> 3) * 256 + (j & 7) * 2 + lg * 64;
#pragma unroll
    for (int r = 0; r < 4; ++r) wadr[r] = (wbase + r * 16) ^ wmask;
  }
  const int tadr = lg * 16;  // + t*64
  const int jb = j * 8;      // byte offset within table row (f16 x4)

  // prologue: tokens(0) -> xc loads; tokens(1) -> tkB
  int4 tkA = *(const int4*)((const char*)tokT + tadr);
  h4 xc0, xc1, xc2, xc3, xn0, xn1, xn2, xn3;
  xc0 = *(const h4*)(tab + tkA.x + jb);
  xc1 = *(const h4*)(tab + tkA.y + jb);
  xc2 = *(const h4*)(tab + tkA.z + jb);
  xc3 = *(const h4*)(tab + tkA.w + jb);
  int4 tkB = *(const int4*)((const char*)tokT + 64 + tadr);

  f16 h0 = (f16)0.f, h1 = (f16)0.f, h2 = (f16)0.f, h3 = (f16)0.f;
  const f16 ONE = (f16)1.f;
  const f16 TWO = (f16)2.f;

#define GATE(HV, CV, I)                                                        \
  {                                                                            \
    const f16 aRh = (f16)aR[I], aZh = (f16)aZ[I], aNh = (f16)aN[I];            \
    const f16 rg = hrcp(ONE + hexp2(CV[0] + aRh));                             \
    const f16 zg = hrcp(ONE + hexp2(CV[1] + aZh));                             \
    const f16 ng = ONE - TWO * hrcp(ONE + hexp2(rg * aNh + CV[2]));            \
    HV = zg * (HV - ng) + ng;                                                  \
    *(f16*)(hw + wadr[I]) = HV;                                                \
  }

#define GRU_BODY(T, P, C0, C1, C2, C3, N0, N1, N2, N3, TKc, TKn)               \
  {                                                                            \
    const char* hb = (const char*)hfrag + (P) * 4096;                          \
    h8 A0 = *(const h8*)(hb + aadr + 0 * 1024);                                \
    h8 A1 = *(const h8*)(hb + aadr + 1 * 1024);                                \
    h8 A2 = *(const h8*)(hb + aadr + 2 * 1024);                                \
    h8 A3 = *(const h8*)(hb + aadr + 3 * 1024);                                \
    N0 = *(const h4*)(tab + TKc.x + jb);                                       \
    N1 = *(const h4*)(tab + TKc.y + jb);                                       \
    N2 = *(const h4*)(tab + TKc.z + jb);                                       \
    N3 = *(const h4*)(tab + TKc.w + jb);                                       \
    {                                                                          \
      const int tt = ((T) + 2 < Tn) ? ((T) + 2) : (Tn - 1);                    \
      TKn = *(const int4*)((const char*)tokT + tt * 64 + tadr);                \
    }                                                                          \
    f4 aR = __builtin_amdgcn_mfma_f32_16x16x32_f16(A0, Bf[0][0], Z4, 0, 0, 0); \
    f4 aZ = __builtin_amdgcn_mfma_f32_16x16x32_f16(A0, Bf[1][0], Z4, 0, 0, 0); \
    f4 aN = __builtin_amdgcn_mfma_f32_16x16x32_f16(A0, Bf[2][0], BH2, 0, 0, 0);\
    aR = __builtin_amdgcn_mfma_f32_16x16x32_f16(A1, Bf[0][1], aR, 0, 0, 0);    \
    aZ = __builtin_amdgcn_mfma_f32_16x16x32_f16(A1, Bf[1][1], aZ, 0, 0, 0);    \
    aN = __builtin_amdgcn_mfma_f32_16x16x32_f16(A1, Bf[2][1], aN, 0, 0, 0);    \
    aR = __builtin_amdgcn_mfma_f32_16x16x32_f16(A2, Bf[0][2], aR, 0, 0, 0);    \
    aZ = __builtin_amdgcn_mfma_f32_16x16x32_f16(A2, Bf[1][2], aZ, 0, 0, 0);    \
    aN = __builtin_amdgcn_mfma_f32_16x16x32_f16(A2, Bf[2][2], aN, 0, 0, 0);    \
    aR = __builtin_amdgcn_mfma_f32_16x16x32_f16(A3, Bf[0][3], aR, 0, 0, 0);    \
    aZ = __builtin_amdgcn_mfma_f32_16x16x32_f16(A3, Bf[1][3], aZ, 0, 0, 0);    \
    aN = __builtin_amdgcn_mfma_f32_16x16x32_f16(A3, Bf[2][3], aN, 0, 0, 0);    \
    char* hw = (char*)hfrag + ((P) ^ 1) * 4096;                                \
    GATE(h0, C0, 0)                                                            \
    GATE(h1, C1, 1)                                                            \
    GATE(h2, C2, 2)                                                            \
    GATE(h3, C3, 3)                                                            \
    asm volatile("s_waitcnt lgkmcnt(0)\n\ts_barrier" ::: "memory");            \
  }

#pragma unroll 1
  for (int t = 0; t < Tn; t += 2) {
    GRU_BODY(t, 0, xc0, xc1, xc2, xc3, xn0, xn1, xn2, xn3, tkB, tkA)
    GRU_BODY(t + 1, 1, xn0, xn1, xn2, xn3, xc0, xc1, xc2, xc3, tkA, tkB)
  }
#undef GRU_BODY
#undef GATE

  feat[(b0 + lg * 4 + 0) * En + dir * Hn + j] = (float)h0;
  feat[(b0 + lg * 4 + 1) * En + dir * Hn + j] = (float)h1;
  feat[(b0 + lg * 4 + 2) * En + dir * Hn + j] = (float)h2;
  feat[(b0 + lg * 4 + 3) * En + dir * Hn + j] = (float)h3;
}

// ---------------- Kernel 3: adapter + LN + proj ----------------
__launch_bounds__(256, 2)
__global__ void epi_k(const float* __restrict__ feat,
                      const int* __restrict__ lang_ids,
                      const float* __restrict__ down_w,
                      const float* __restrict__ down_b,
                      const float* __restrict__ up_w,
                      const float* __restrict__ up_b,
                      const float* __restrict__ ln_g,
                      const float* __restrict__ ln_b,
                      const float* __restrict__ proj_w,
                      const float* __restrict__ proj_b,
                      float* __restrict__ out) {
  const int tid = threadIdx.x;
  const int wv = tid >> 6, ln = tid & 63;
  const int b0 = blockIdx.x * 8;

  __shared__ float fl[8][En];
  __shared__ f16 yA[16][En + 8];

#pragma unroll
  for (int s = 0; s < 8; ++s) fl[s][tid] = feat[(b0 + s) * En + tid];
  {
    f16* z = &yA[0][0];
    for (int i = tid; i < 16 * (En + 8); i += 256) z[i] = (f16)0.f;
  }
  __syncthreads();

#pragma unroll 1
  for (int si = 0; si < 2; ++si) {
    const int s = wv * 2 + si;
    const int lang = lang_ids[b0 + s];

    const int d = ln & 31, hf = ln >> 5;
    const f4* dwv = (const f4*)(down_w + (lang * BNn + d) * En + hf * 128);
    const f4* fsv = (const f4*)&fl[s][hf * 128];
    float pacc = 0.f;
#pragma unroll
    for (int q = 0; q < 32; ++q) {
      f4 a = fsv[q], w = dwv[q];
      pacc = fmaf(a.x, w.x, pacc);
      pacc = fmaf(a.y, w.y, pacc);
      pacc = fmaf(a.z, w.z, pacc);
      pacc = fmaf(a.w, w.w, pacc);
    }
    pacc += __shfl_xor(pacc, 32);
    const float hv = pacc + down_b[lang * BNn + d];
    const float hid = 0.5f * hv * (1.0f + erff(hv * 0.70710678118f));

    float hh[32];
#pragma unroll
    for (int dd = 0; dd < 32; ++dd) hh[dd] = __shfl(hid, dd);

    const int e0 = ln * 4;
    float x[4];
    float s1 = 0.f, s2 = 0.f;
#pragma unroll
    for (int i = 0; i < 4; ++i) {
      const f4* ur = (const f4*)(up_w + (lang * En + e0 + i) * BNn);
      float a = 0.f;
#pragma unroll
      for (int q = 0; q < 8; ++q) {
        f4 u = ur[q];
        a = fmaf(hh[q * 4 + 0], u.x, a);
        a = fmaf(hh[q * 4 + 1], u.y, a);
        a = fmaf(hh[q * 4 + 2], u.z, a);
        a = fmaf(hh[q * 4 + 3], u.w, a);
      }
      x[i] = a + fl[s][e0 + i] + up_b[lang * En + e0 + i];
      s1 += x[i];
      s2 = fmaf(x[i], x[i], s2);
    }
#pragma unroll
    for (int off = 32; off >= 1; off >>= 1) {
      s1 += __shfl_xor(s1, off);
      s2 += __shfl_xor(s2, off);
    }
    const float mu = s1 * (1.0f / En);
    const float var = s2 * (1.0f / En) - mu * mu;
    const float rs = rsqrtf(var + 1e-5f);
#pragma unroll
    for (int i = 0; i < 4; ++i) {
      const float yv = (x[i] - mu) * rs * ln_g[lang * En + e0 + i] + ln_b[lang * En + e0 + i];
      yA[s][e0 + i] = (f16)yv;
    }
  }
  __syncthreads();

  const int lr = ln & 15, lg = ln >> 4;
  f4 acc[4];
#pragma unroll
  for (int tt = 0; tt < 4; ++tt) {
    const float pb = proj_b[wv * 64 + tt * 16 + lr];
    acc[tt] = (f4){pb, pb, pb, pb};
  }
#pragma unroll
  for (int kk = 0; kk < 8; ++kk) {
    h8 aF = *(const h8*)(&yA[lr][kk * 32 + lg * 8]);
#pragma unroll
    for (int tt = 0; tt < 4; ++tt) {
      const int o0 = wv * 64 + tt * 16;
      const float* pw = proj_w + (o0 + lr) * En + kk * 32 + lg * 8;
      h8 bF;
#pragma unroll
      for (int i = 0; i < 8; ++i) bF[i] = (f16)pw[i];
      acc[tt] = __builtin_amdgcn_mfma_f32_16x16x32_f16(aF, bF, acc[tt], 0, 0, 0);
    }
  }
  if (lg < 2) {
#pragma unroll
    for (int tt = 0; tt < 4; ++tt) {
      const int o0 = wv * 64 + tt * 16;
#pragma unroll
      for (int r = 0; r < 4; ++r)
        out[(b0 + lg * 4 + r) * On + o0 + lr] = acc[tt][r];
    }
  }
}

extern "C" void kernel_launch(void* const* d_in, const int* in_sizes, int n_in,
                              void* d_out, int out_size, void* d_ws, size_t ws_size,
                              hipStream_t stream) {
  const int* tokens = (const int*)d_in[0];
  const int* lang_ids = (const int*)d_in[1];
  const float* emb = (const float*)d_in[2];
  const float* w_ih_f = (const float*)d_in[3];
  const float* w_hh_f = (const float*)d_in[4];
  const float* b_ih_f = (const float*)d_in[5];
  const float* b_hh_f = (const float*)d_in[6];
  const float* w_ih_b = (const float*)d_in[7];
  const float* w_hh_b = (const float*)d_in[8];
  const float* b_ih_b = (const float*)d_in[9];
  const float* b_hh_b = (const float*)d_in[10];
  const float* down_w = (const float*)d_in[11];
  const float* down_b = (const float*)d_in[12];
  const float* up_w = (const float*)d_in[13];
  const float* up_b = (const float*)d_in[14];
  const float* ln_g = (const float*)d_in[15];
  const float* ln_b = (const float*)d_in[16];
  const float* proj_w = (const float*)d_in[17];
  const float* proj_b = (const float*)d_in[18];

  f16* xt = (f16*)d_ws;                                       // [2][256][128][4] f16 = 512KB
  float* feat = (float*)((char*)d_ws + 2 * Vn * Hn * 4 * 2);  // [2048][256] f32

  build_table_k<<<dim3(512), dim3(128), 0, stream>>>(emb, w_ih_f, b_ih_f, b_hh_f,
                                                     w_ih_b, b_ih_b, b_hh_b, xt);
  gru_k<<<dim3(256), dim3(512), 0, stream>>>(tokens, w_hh_f, b_hh_f, w_hh_b, b_hh_b, xt, feat);
  epi_k<<<dim3(256), dim3(256), 0, stream>>>(feat, lang_ids, down_w, down_b, up_w, up_b,
                                             ln_g, ln_b, proj_w, proj_b, (float*)d_out);
}